// Round 8
// baseline (13.178 us; speedup 1.0000x reference)
//
#include <hip/hip_runtime.h>

#define WAVES 4                      // waves per block (256 thr)
#define RPW   2                      // rows per wave: row0=LDS path, row1=readlane path
#define RPB   (WAVES * RPW)          // 8 rows/block -> 512 blocks (2/CU)
#define GROUPS   16
#define GRP_BLKS 32                  // 512 / 16
#define TK_SH 54                     // ticket field [54,64)
#define LS_SH 25                     // loss Q3 field [25,54)
#define LS_MASK ((1ull << 29) - 1)
#define CT_MASK ((1ull << 25) - 1)
#define POISON  0xAAAAAAAAAAAAAAAAull

// Single fused kernel. Body is pipe-balanced: each wave computes one row via
// LDS b128 broadcast (LDS pipe) and one row via v_readlane broadcast from its
// own registers (VALU pipe) -> LDS work halves (hidden), VALU becomes the
// bound at ~1.9us instead of LDS 2.6us. Tail: two-level packed-atomic tree
// {ticket:10 | loss_Q3:29 | count:25}, poison-epoch-safe, self-resetting
// (proven R4-R7).
__global__ __launch_bounds__(256) void prl_one(
    const float* __restrict__ scores,
    const int* __restrict__ top_mask,
    const int* __restrict__ valid_mask,
    unsigned long long* __restrict__ gacc,   // 16 accs, 64B stride
    unsigned long long* __restrict__ facc,   // final acc
    float* __restrict__ out)
{
    __shared__ float a_sh[WAVES][128];       // only the LDS-path row per wave
    __shared__ float wl[WAVES];
    __shared__ unsigned wc[WAVES];

    const int w    = threadIdx.x >> 6;
    const int lane = threadIdx.x & 63;
    const int r0   = blockIdx.x * RPB + w * RPW;
    const int c0   = lane * 2;

    float2 s[RPW]; int2 t[RPW], v[RPW];
    #pragma unroll
    for (int k = 0; k < RPW; ++k) {          // all 6 loads in flight at once
        const size_t b = (size_t)(r0 + k) * 128 + c0;
        s[k] = *(const float2*)(scores + b);
        t[k] = *(const int2*)(top_mask + b);
        v[k] = *(const int2*)(valid_mask + b);
    }

    // a_j = margin + s_j for non-top-valid j, else -1e30 sentinel:
    // max(-1e30, s_i) = s_i and the epilogue's -128*s_i cancels it -> 0.
    float2 aL, aR;
    aL.x = ((t[0].x == 0) & (v[0].x == 1)) ? (1.0f + s[0].x) : -1e30f;
    aL.y = ((t[0].y == 0) & (v[0].y == 1)) ? (1.0f + s[0].y) : -1e30f;
    aR.x = ((t[1].x == 0) & (v[1].x == 1)) ? (1.0f + s[1].x) : -1e30f;
    aR.y = ((t[1].y == 0) & (v[1].y == 1)) ? (1.0f + s[1].y) : -1e30f;

    *(float2*)(&a_sh[w][c0]) = aL;           // stage only the LDS-path row
    __builtin_amdgcn_wave_barrier();         // same-wave LDS write->read

    float2 acL, acR;
    acL.x = acL.y = acR.x = acR.y = 0.f;

    // --- row 0: LDS b128 broadcast path (LDS pipe) ---
    #pragma unroll 4
    for (int j = 0; j < 128; j += 4) {
        const float4 aj = *(const float4*)(&a_sh[w][j]);   // broadcast b128
        acL.x += fmaxf(aj.x, s[0].x);
        acL.y += fmaxf(aj.x, s[0].y);
        acL.x += fmaxf(aj.y, s[0].x);
        acL.y += fmaxf(aj.y, s[0].y);
        acL.x += fmaxf(aj.z, s[0].x);
        acL.y += fmaxf(aj.z, s[0].y);
        acL.x += fmaxf(aj.w, s[0].x);
        acL.y += fmaxf(aj.w, s[0].y);
    }

    // --- row 1: v_readlane broadcast path (VALU pipe, zero LDS) ---
    const unsigned aRx = __float_as_uint(aR.x);
    const unsigned aRy = __float_as_uint(aR.y);
    #pragma unroll
    for (int jl = 0; jl < 64; ++jl) {
        const float alo = __uint_as_float(__builtin_amdgcn_readlane(aRx, jl)); // col 2*jl
        const float ahi = __uint_as_float(__builtin_amdgcn_readlane(aRy, jl)); // col 2*jl+1
        acR.x += fmaxf(alo, s[1].x);
        acR.y += fmaxf(alo, s[1].y);
        acR.x += fmaxf(ahi, s[1].x);
        acR.y += fmaxf(ahi, s[1].y);
    }

    float ll = 0.f;
    unsigned cw = 0;
    // per anchor: sum_j max(a_j,s_i) - 128*s_i == sum_j relu(a_j - s_i)
    ll += (t[0].x == 1) ? fmaf(-128.f, s[0].x, acL.x) : 0.f;
    ll += (t[0].y == 1) ? fmaf(-128.f, s[0].y, acL.y) : 0.f;
    ll += (t[1].x == 1) ? fmaf(-128.f, s[1].x, acR.x) : 0.f;
    ll += (t[1].y == 1) ? fmaf(-128.f, s[1].y, acR.y) : 0.f;
    #pragma unroll
    for (int k = 0; k < RPW; ++k) {
        const unsigned tc = (unsigned)(__popcll(__ballot(t[k].x == 1)) +
                                       __popcll(__ballot(t[k].y == 1)));
        const unsigned nc = (unsigned)(__popcll(__ballot((t[k].x == 0) & (v[k].x == 1))) +
                                       __popcll(__ballot((t[k].y == 0) & (v[k].y == 1))));
        cw += tc * nc;                       // exact per-row (#top)*(#ntv)
    }
    #pragma unroll
    for (int o = 32; o > 0; o >>= 1)
        ll += __shfl_xor(ll, o, 64);

    if (lane == 0) { wl[w] = ll; wc[w] = cw; }
    __syncthreads();

    if (threadIdx.x == 0) {
        double bl = 0.0; unsigned long long bc = 0;
        #pragma unroll
        for (int k = 0; k < WAVES; ++k) { bl += (double)wl[k]; bc += wc[k]; }
        const unsigned long long lq =
            (unsigned long long)__double2ll_rn(bl * 8.0);          // Q3
        const unsigned long long pack = (1ull << TK_SH) + (lq << LS_SH) + bc;

        // ---- level 1: group accumulator (contention split 16 ways) ----
        unsigned long long* ga = gacc + (blockIdx.x >> 5) * 8;     // 64B stride
        const unsigned long long old = atomicAdd(ga, pack);
        // fresh tickets <= 31; poison residue 682: disjoint at >=512.
        const unsigned long long B = ((old >> TK_SH) >= 512) ? POISON : 0ull;
        const unsigned long long prog = old - B;                   // exact

        if ((prog >> TK_SH) == (unsigned long long)(GRP_BLKS - 1)) {
            const unsigned long long gtot = prog + pack;           // group totals
            const unsigned long long gl = (gtot >> LS_SH) & LS_MASK;
            const unsigned long long gc = gtot & CT_MASK;

            // ---- level 2: final accumulator (16 forwards) ----
            const unsigned long long fpack = (1ull << TK_SH) + (gl << LS_SH) + gc;
            const unsigned long long fold = atomicAdd(facc, fpack);
            const unsigned long long fB = ((fold >> TK_SH) >= 512) ? POISON : 0ull;
            const unsigned long long fprog = fold - fB;

            // self-reset own group acc (value carries a dep on gtot; bit63=0)
            atomicExch(ga, gtot >> 63);

            if ((fprog >> TK_SH) == (unsigned long long)(GROUPS - 1)) {
                const unsigned long long ftot = fprog + fpack;
                const unsigned long long cnt = ftot & CT_MASK;
                const double tl = (double)((ftot >> LS_SH) & LS_MASK) * 0.125;
                out[0] = (cnt > 0) ? (float)(tl / (double)cnt) : (float)tl;
                atomicExch(facc, ftot >> 63);   // self-reset final acc
            }
        }
    }
}

extern "C" void kernel_launch(void* const* d_in, const int* in_sizes, int n_in,
                              void* d_out, int out_size, void* d_ws, size_t ws_size,
                              hipStream_t stream) {
    const float* scores = (const float*)d_in[0];
    const int*   top    = (const int*)d_in[1];
    const int*   valid  = (const int*)d_in[2];

    const int batch   = in_sizes[0] / 128;   // 4096 rows
    const int nblocks = batch / RPB;         // 512

    // ws: [0, 16*64): group accs (64B stride); [1024, 1032): final acc
    unsigned long long* gacc = (unsigned long long*)d_ws;
    unsigned long long* facc = (unsigned long long*)((char*)d_ws + GROUPS * 64);

    prl_one<<<nblocks, 256, 0, stream>>>(scores, top, valid,
                                         gacc, facc, (float*)d_out);
}